// Round 15
// baseline (209.771 us; speedup 1.0000x reference)
//
#include <hip/hip_runtime.h>

// H2G2: 2-layer RGCN (R=4, per-relation mean) + mean-pool + linear.
// R10 (231us, layer 47): register-resident fused layer. R11 FAILED: VGPR cap
//   -> scratch spill. R12 (229.6): channel-split wave pair; layer pinned 47.0.
// R13 FAILED: random 4B global writes = line RMW. R14 FAILED: grid.sync
//   ~80-90us each w/ idle grid. R15: CAP-bucket OK; per-element device
//   atomics FAILED (3.2M = 150us). R16 (219.6): 6-dispatch pipeline.
// R17 FAILED: 8-edge unroll -> occ crash. MLP model: layer ~ 1/(waves x
//   depth) until ~96 lines/CU, then per-XCD random-fill-rate floor ~0.9
//   lines/cy (R21 null proves rate-bound). Gather FROZEN. FETCH 52MB compuls.
// R18 (275): LDS-first pooling OK; 1-block uncached cls = 70us serial tail.
// R19 (232.4): in-layer CSR paid twice. R20 (218.3): CSR once in build.
// R22 (229.9): fine bins broke bin write coalescing. REVERTED.
// R23 (219.4): XCD swizzle killed build over-fetch (63.5->49.2MB) but only
//   -2.4us -> Phase A is barrier/latency-bound, not fill-bound.
// R24 (209.4, BEST): shuffle-scans + sbkt tag cut ~20 barriers -> -10us.
//   Accounting: kernels ~143us, ~66us = 5 dispatch boundaries @ ~13us.
// R25: delete the cls dispatch. Pool->matmul commute: each read block
//   multiplies its pgs[s][h] partial by clas_w (64x4 MAC tail, 1 wave) and
//   atomicAdds 4 floats/graph-slot into gout (~12.5k atomics total, 256x
//   below R15's failure scale). gout bias-init in work (gsum deleted).
//   Pipeline: memset -> work -> build -> read(+pool+cls) = 4+1 dispatches.

#define RR 4
#define HH 64
#define KK 320         // (RR+1)*HH
#define LWN (HH * KK)  // weights per layer = 20480
#define EPB 2048       // edges per bin chunk
#define CAP 6144       // per-256-node-bucket capacity (mean 4096, +32 sigma)
#define NSLOT 8        // LDS pool slots
#define VCAP 1024      // per-build-block edge list cap (mean 512, +22 sigma)

using frag_ab = __attribute__((ext_vector_type(8))) short;
using frag_cd = __attribute__((ext_vector_type(4))) float;

__device__ inline short f2bf(float f) {
    unsigned u = __builtin_bit_cast(unsigned, f);
    unsigned r = u + 0x7fffu + ((u >> 16) & 1u);  // RNE
    return (short)(r >> 16);
}
__device__ inline float bf2f(short s) {
    unsigned u = ((unsigned)(unsigned short)s) << 16;
    return __builtin_bit_cast(float, u);
}

// ---- shared gather accumulate macro ----
#define ACCM(P, F)                                                            \
    {                                                                         \
        int r_ = (P) & 3;                                                     \
        float s0_ = (r_ == 0) ? 1.f : 0.f;                                    \
        float s1_ = (r_ == 1) ? 1.f : 0.f;                                    \
        float s2_ = (r_ == 2) ? 1.f : 0.f;                                    \
        float s3_ = (r_ == 3) ? 1.f : 0.f;                                    \
        _Pragma("unroll") for (int j = 0; j < 8; ++j) {                       \
            float v_ = bf2f((F)[j]);                                          \
            acc[0][j] += v_ * s0_;                                            \
            acc[1][j] += v_ * s1_;                                            \
            acc[2][j] += v_ * s2_;                                            \
            acc[3][j] += v_ * s3_;                                            \
        }                                                                     \
    }

// ---- work: bin(shuffle-scan) | weights | gstart | gout-bias-init | x conv ----
__global__ __launch_bounds__(256) void work_kernel(
    const int* __restrict__ src, const int* __restrict__ dst,
    const int* __restrict__ et, int E,
    int* __restrict__ cur, int* __restrict__ tmp,
    const float* __restrict__ basis1, const float* __restrict__ comp1, const float* __restrict__ root1,
    const float* __restrict__ basis2, const float* __restrict__ comp2, const float* __restrict__ root2,
    short* __restrict__ W1t, short* __restrict__ W2t,
    const int* __restrict__ batch, int* __restrict__ gstart, int N, int G,
    const float* __restrict__ x, short* __restrict__ Xb,
    float* __restrict__ gout, const float* __restrict__ clas_b,
    int ebl, int wbl, int nb, int gzb) {
    __shared__ int hist[256];
    __shared__ int lscan[256];
    __shared__ int lbase[256];
    __shared__ int lc2[256];
    __shared__ int wsum[4];
    __shared__ int sbuf[EPB];
    __shared__ unsigned char sbkt[EPB];
    const int bid = blockIdx.x;
    const int t = threadIdx.x;

    if (bid < ebl) {  // ---- bin: LDS-staged bucket scatter into CAP regions ----
        const int e0 = bid * EPB;
        const int e1 = min(e0 + EPB, E);
        hist[t] = 0;
        __syncthreads();
        for (int e = e0 + t; e < e1; e += 256) atomicAdd(&hist[dst[e] >> 8], 1);
        __syncthreads();
        int v = hist[t];
        // shuffle inclusive scan over 256 threads (4 waves)
        const int lane = t & 63, w = t >> 6;
        int sv = v;
#pragma unroll
        for (int off = 1; off < 64; off <<= 1) {
            int u = __shfl_up(sv, off, 64);
            if (lane >= off) sv += u;
        }
        if (lane == 63) wsum[w] = sv;
        __syncthreads();
        int wpre = 0;
#pragma unroll
        for (int i = 0; i < 4; ++i) wpre += (i < w) ? wsum[i] : 0;
        sv += wpre;                 // inclusive
        lscan[t] = sv - v;          // exclusive
        lbase[t] = v ? t * CAP + atomicAdd(&cur[t], v) : 0;  // reserve
        lc2[t] = 0;
        __syncthreads();
        for (int e = e0 + t; e < e1; e += 256) {
            int d = dst[e];
            int b = d >> 8;
            int p = (src[e] << 10) | (et[e] << 8) | (d & 255);
            int pos = lscan[b] + atomicAdd(&lc2[b], 1);
            sbuf[pos] = p;
            sbkt[pos] = (unsigned char)b;
        }
        __syncthreads();
        int tot = e1 - e0;
        for (int i = t; i < tot; i += 256) {
            int b = sbkt[i];
            int idx = lbase[b] + (i - lscan[b]);
            if (idx - b * CAP < CAP) tmp[idx] = sbuf[i];  // overflow shield
        }
    } else if (bid < ebl + wbl) {  // ---- weights: Wt[c*320+k] = Wstack[k][c] ----
        int w = (bid - ebl) * 256 + t;
        int layer = w / LWN;
        int rem = w - layer * LWN;
        int c = rem / KK;
        int k = rem - c * KK;
        const float* basis = layer ? basis2 : basis1;
        const float* comp  = layer ? comp2  : comp1;
        const float* root  = layer ? root2  : root1;
        short* Wt          = layer ? W2t    : W1t;
        float v;
        if (k < HH) {
            v = root[k * HH + c];
        } else {
            int r = (k >> 6) - 1, kk = k & 63;
            v = 0.f;
#pragma unroll
            for (int b = 0; b < RR; ++b) v += comp[r * RR + b] * basis[(b * HH + kk) * HH + c];
        }
        Wt[c * KK + k] = f2bf(v);
    } else if (bid < ebl + wbl + nb) {  // ---- gstart ----
        int i = (bid - ebl - wbl) * 256 + t;
        if (i < N) {
            int b1 = batch[i];
            int b0 = (i == 0) ? -1 : batch[i - 1];
            for (int g = b0 + 1; g <= b1; ++g) gstart[g] = i;
            if (i == N - 1)
                for (int g = b1 + 1; g <= G; ++g) gstart[g] = N;
        }
    } else if (bid < ebl + wbl + nb + gzb) {  // ---- gout = bias (classifier base) ----
        int i = (bid - ebl - wbl - nb) * 256 + t;
        if (i < G * 4) gout[i] = clas_b[i & 3];
    } else {  // ---- convert x fp32 -> bf16 ----
        int i4 = (bid - ebl - wbl - nb - gzb) * 256 + t;
        int base = i4 * 4;
        if (base < N * 64) {
            float4 f = *(const float4*)&x[base];
            short4 s;
            s.x = f2bf(f.x); s.y = f2bf(f.y); s.z = f2bf(f.z); s.w = f2bf(f.w);
            *(short4*)&Xb[base] = s;
        }
    }
}

// ---- layer_build (L1, 256 thr / 32 nodes, XCD-swizzled): Phase A CSR
//      (shuffle scan) -> persist rp4/kend/eidxg; Phase B = FROZEN gather. ----
__global__ __launch_bounds__(256) void layer_build_kernel(
    const int* __restrict__ curg,
    const int* __restrict__ tmp,
    const short* __restrict__ Xb,
    const short* __restrict__ Wt,
    const float* __restrict__ bias,
    short* __restrict__ out, int n,
    int4* __restrict__ rp4g, int* __restrict__ kendg,
    int* __restrict__ eidxg) {
    __shared__ short xpack[2][64][32];  // 8KB
    __shared__ int cnt[128];
    __shared__ int off[129];
    __shared__ int curs[128];
    __shared__ int wsumA[2];
    __shared__ int elist[VCAP];         // 4KB
    const int t = threadIdx.x;
    const int wv = t >> 6;
    const int pair = wv >> 1;
    const int ws = wv & 1;
    const int l = t & 63;
    const int m = l & 15;
    const int quad = l >> 4;

    // ---- XCD-aware bijective swizzle (m204): bucket's 8 blocks -> one XCD ----
    const int nwg = (int)gridDim.x;
    const int orig = blockIdx.x;
    const int q = nwg >> 3, r = nwg & 7;
    const int xcd = orig & 7, idx = orig >> 3;
    const int chunk = (xcd < r ? xcd * (q + 1) : r * (q + 1) + (xcd - r) * q) + idx;

    const int node0 = chunk * 32;
    const int node = node0 + pair * 16 + m;
    const bool valid = node < n;

    // ---- Phase A ----
    const int b = node0 >> 8;
    const int dl0 = node0 & 255;
    const int tb = b * CAP;
    const int len = min(curg[b], CAP);

    for (int i = t; i < 128; i += 256) cnt[i] = 0;
    __syncthreads();
    for (int i = t; i < len; i += 256) {
        int e = tmp[tb + i];
        int w = (e & 255) - dl0;
        if ((unsigned)w < 32u) atomicAdd(&cnt[(w << 2) | ((e >> 8) & 3)], 1);
    }
    __syncthreads();
    // shuffle scan of cnt[0..127] (2 waves)
    {
        int v128 = (t < 128) ? cnt[t] : 0;
        int sv = v128;
#pragma unroll
        for (int o = 1; o < 64; o <<= 1) {
            int u = __shfl_up(sv, o, 64);
            if (l >= o) sv += u;
        }
        if (t == 63) wsumA[0] = sv;
        if (t == 127) wsumA[1] = sv;
        __syncthreads();
        if (t < 128) {
            int incl = sv + ((t >= 64) ? wsumA[0] : 0);
            int ex = incl - v128;
            off[t] = ex;
            curs[t] = ex;
            if (t == 127) off[128] = incl;
        }
        __syncthreads();
    }
    for (int i = t; i < len; i += 256) {
        int e = tmp[tb + i];
        int w = (e & 255) - dl0;
        if ((unsigned)w < 32u) {
            int pos = atomicAdd(&curs[(w << 2) | ((e >> 8) & 3)], 1);
            if (pos < VCAP) elist[pos] = ((e >> 10) << 2) | ((e >> 8) & 3);
        }
    }
    __syncthreads();

    // ---- persist CSR (overlaps with Phase B issue) ----
    const int eb = chunk * VCAP;
    if (t < 32 && node0 + t < n) {
        int c4 = t << 2;
        rp4g[node0 + t] = make_int4(eb + min(off[c4], VCAP), eb + min(off[c4 + 1], VCAP),
                                    eb + min(off[c4 + 2], VCAP), eb + min(off[c4 + 3], VCAP));
        kendg[node0 + t] = eb + min(off[c4 + 4], VCAP);
    }
    {
        int fill = min(off[128], VCAP);
        for (int i = t; i < fill; i += 256) eidxg[eb + i] = elist[i];
    }

    // ---- Phase B: FROZEN gather from LDS elist ----
    float acc[4][8];
#pragma unroll
    for (int r2 = 0; r2 < 4; ++r2)
#pragma unroll
        for (int j = 0; j < 8; ++j) acc[r2][j] = 0.f;

    const int w4 = ((pair << 4) | m) << 2;
    const int k0 = min(off[w4], VCAP);
    const int k1 = min(off[w4 + 4], VCAP);
    float4 iv;
    iv.x = 1.0f / fmaxf((float)cnt[w4 + 0], 1.0f);
    iv.y = 1.0f / fmaxf((float)cnt[w4 + 1], 1.0f);
    iv.z = 1.0f / fmaxf((float)cnt[w4 + 2], 1.0f);
    iv.w = 1.0f / fmaxf((float)cnt[w4 + 3], 1.0f);
    const short* xbq = Xb + ws * 32 + quad * 8;

    int k = k0;
    for (; k + 3 < k1; k += 4) {
        int p0 = elist[k];
        int p1 = elist[k + 1];
        int p2 = elist[k + 2];
        int p3 = elist[k + 3];
        const short* a0p = xbq + (size_t)(p0 >> 2) * 64;
        const short* a1p = xbq + (size_t)(p1 >> 2) * 64;
        const short* a2p = xbq + (size_t)(p2 >> 2) * 64;
        const short* a3p = xbq + (size_t)(p3 >> 2) * 64;
        frag_ab f0 = *(const frag_ab*)a0p;
        frag_ab f1 = *(const frag_ab*)a1p;
        frag_ab f2 = *(const frag_ab*)a2p;
        frag_ab f3 = *(const frag_ab*)a3p;
        ACCM(p0, f0)
        ACCM(p1, f1)
        ACCM(p2, f2)
        ACCM(p3, f3)
    }
    for (; k < k1; ++k) {
        int p0 = elist[k];
        const short* a0p = xbq + (size_t)(p0 >> 2) * 64;
        frag_ab f0 = *(const frag_ab*)a0p;
        ACCM(p0, f0)
    }

    frag_ab y[4];
    {
        float s0 = iv.x, s1 = iv.y, s2 = iv.z, s3 = iv.w;
#pragma unroll
        for (int j = 0; j < 8; ++j) {
            y[0][j] = f2bf(acc[0][j] * s0);
            y[1][j] = f2bf(acc[1][j] * s1);
            y[2][j] = f2bf(acc[2][j] * s2);
            y[3][j] = f2bf(acc[3][j] * s3);
        }
    }

    if (ws == 1) {
#pragma unroll
        for (int r2 = 0; r2 < 4; ++r2)
            *(frag_ab*)&xpack[pair][l][r2 * 8] = y[r2];
    }
    __syncthreads();
    if (ws == 1) return;

    frag_ab a[10];
    a[0] = frag_ab{};
    a[1] = frag_ab{};
    if (valid) {
        const short* xr = Xb + (size_t)node * 64 + quad * 8;
        a[0] = *(const frag_ab*)xr;
        a[1] = *(const frag_ab*)(xr + 32);
    }
#pragma unroll
    for (int r2 = 0; r2 < 4; ++r2) {
        a[2 + 2 * r2] = y[r2];
        a[3 + 2 * r2] = *(const frag_ab*)&xpack[pair][l][r2 * 8];
    }

    const int nrow_base = node0 + pair * 16 + quad * 4;
#pragma unroll
    for (int ct = 0; ct < 4; ++ct) {
        const short* bp = Wt + (size_t)(ct * 16 + m) * KK + quad * 8;
        frag_cd c = {0.f, 0.f, 0.f, 0.f};
#pragma unroll
        for (int f = 0; f < 10; ++f) {
            frag_ab bf = *(const frag_ab*)(bp + f * 32);
            c = __builtin_amdgcn_mfma_f32_16x16x32_bf16(a[f], bf, c, 0, 0, 0);
        }
        int col = ct * 16 + m;
        float bv = bias[col];
#pragma unroll
        for (int r2 = 0; r2 < 4; ++r2) {
            int nr = nrow_base + r2;
            if (nr < n) out[(size_t)nr * 64 + col] = f2bf(fmaxf(c[r2] + bv, 0.f));
        }
    }
}

// ---- layer_read (L2, 256 thr / 32 nodes): gather from persisted CSR +
//      LDS-first pooling + commuted classifier -> gout atomics (cls deleted). ----
__global__ __launch_bounds__(256) void layer_read_kernel(
    const int4* __restrict__ rp4g, const int* __restrict__ kendg,
    const int* __restrict__ eidxg,
    const short* __restrict__ Xb,
    const short* __restrict__ Wt,
    const float* __restrict__ bias,
    int n, const int* __restrict__ batch,
    const int* __restrict__ gstart, const float* __restrict__ clas_w,
    float* __restrict__ gout) {
    __shared__ short xpack[2][64][32];  // 8KB
    __shared__ float pgs[NSLOT * 64];   // 2KB
    const int t = threadIdx.x;
    const int wv = t >> 6;
    const int pair = wv >> 1;
    const int ws = wv & 1;
    const int l = t & 63;
    const int m = l & 15;
    const int quad = l >> 4;
    const int node0 = blockIdx.x * 32;
    const int node = node0 + pair * 16 + m;
    const bool valid = node < n;

    for (int i = t; i < NSLOT * 64; i += 256) pgs[i] = 0.f;

    float acc[4][8];
#pragma unroll
    for (int r = 0; r < 4; ++r)
#pragma unroll
        for (int j = 0; j < 8; ++j) acc[r][j] = 0.f;

    int k0 = 0, k1 = 0;
    float4 iv = make_float4(0.f, 0.f, 0.f, 0.f);
    if (valid) {
        int4 r4 = rp4g[node];
        int kend = kendg[node];
        k0 = r4.x;
        k1 = kend;
        iv.x = 1.0f / fmaxf((float)(r4.y - r4.x), 1.0f);
        iv.y = 1.0f / fmaxf((float)(r4.z - r4.y), 1.0f);
        iv.z = 1.0f / fmaxf((float)(r4.w - r4.z), 1.0f);
        iv.w = 1.0f / fmaxf((float)(kend - r4.w), 1.0f);
    }
    const short* xbq = Xb + ws * 32 + quad * 8;

    int k = k0;
    for (; k + 3 < k1; k += 4) {  // FROZEN 4-deep
        int p0 = eidxg[k];
        int p1 = eidxg[k + 1];
        int p2 = eidxg[k + 2];
        int p3 = eidxg[k + 3];
        const short* a0p = xbq + (size_t)(p0 >> 2) * 64;
        const short* a1p = xbq + (size_t)(p1 >> 2) * 64;
        const short* a2p = xbq + (size_t)(p2 >> 2) * 64;
        const short* a3p = xbq + (size_t)(p3 >> 2) * 64;
        frag_ab f0 = *(const frag_ab*)a0p;
        frag_ab f1 = *(const frag_ab*)a1p;
        frag_ab f2 = *(const frag_ab*)a2p;
        frag_ab f3 = *(const frag_ab*)a3p;
        ACCM(p0, f0)
        ACCM(p1, f1)
        ACCM(p2, f2)
        ACCM(p3, f3)
    }
    for (; k < k1; ++k) {
        int p0 = eidxg[k];
        const short* a0p = xbq + (size_t)(p0 >> 2) * 64;
        frag_ab f0 = *(const frag_ab*)a0p;
        ACCM(p0, f0)
    }

    frag_ab y[4];
    {
        float s0 = iv.x, s1 = iv.y, s2 = iv.z, s3 = iv.w;
#pragma unroll
        for (int j = 0; j < 8; ++j) {
            y[0][j] = f2bf(acc[0][j] * s0);
            y[1][j] = f2bf(acc[1][j] * s1);
            y[2][j] = f2bf(acc[2][j] * s2);
            y[3][j] = f2bf(acc[3][j] * s3);
        }
    }

    if (ws == 1) {
#pragma unroll
        for (int r = 0; r < 4; ++r)
            *(frag_ab*)&xpack[pair][l][r * 8] = y[r];
    }
    __syncthreads();

    const int nrow_base = node0 + pair * 16 + quad * 4;
    const int batch_base = batch[node0];

    if (ws == 0) {
        frag_ab a[10];
        a[0] = frag_ab{};
        a[1] = frag_ab{};
        if (valid) {
            const short* xr = Xb + (size_t)node * 64 + quad * 8;
            a[0] = *(const frag_ab*)xr;
            a[1] = *(const frag_ab*)(xr + 32);
        }
#pragma unroll
        for (int r = 0; r < 4; ++r) {
            a[2 + 2 * r] = y[r];
            a[3 + 2 * r] = *(const frag_ab*)&xpack[pair][l][r * 8];
        }

        int bv4[4];
        if (nrow_base + 3 < n) {
            int4 bb = *(const int4*)&batch[nrow_base];
            bv4[0] = bb.x; bv4[1] = bb.y; bv4[2] = bb.z; bv4[3] = bb.w;
        } else {
#pragma unroll
            for (int r = 0; r < 4; ++r)
                bv4[r] = (nrow_base + r < n) ? batch[nrow_base + r] : 0;
        }

#pragma unroll
        for (int ct = 0; ct < 4; ++ct) {
            const short* bp = Wt + (size_t)(ct * 16 + m) * KK + quad * 8;
            frag_cd c = {0.f, 0.f, 0.f, 0.f};
#pragma unroll
            for (int f = 0; f < 10; ++f) {
                frag_ab bf = *(const frag_ab*)(bp + f * 32);
                c = __builtin_amdgcn_mfma_f32_16x16x32_bf16(a[f], bf, c, 0, 0, 0);
            }
            int col = ct * 16 + m;
            float bv = bias[col];
#pragma unroll
            for (int r = 0; r < 4; ++r) {
                int nr = nrow_base + r;
                if (nr < n) {
                    float v = fmaxf(c[r] + bv, 0.f);
                    int g = bv4[r] - batch_base;
                    if (g < NSLOT) {
                        atomicAdd(&pgs[g * 64 + col], v);
                    } else {
                        // rare overflow: commuted classifier per element
                        int gg = bv4[r];
                        float invc = 1.0f / fmaxf((float)(gstart[gg + 1] - gstart[gg]), 1.0f);
                        float vm = v * invc;
#pragma unroll
                        for (int cc = 0; cc < 4; ++cc)
                            atomicAdd(&gout[gg * 4 + cc], vm * clas_w[col * 4 + cc]);
                    }
                }
            }
        }
    }

    __syncthreads();
    // ---- commuted classifier: pgs[s][:] @ clas_w -> 4 atomics per slot ----
    int node_last = min(node0 + 31, n - 1);
    int gspan = batch[node_last] - batch_base;
    int nslots = min(gspan + 1, NSLOT);
    if (t < nslots * 4) {
        int s = t >> 2, cc = t & 3;
        int g = batch_base + s;
        float invc = 1.0f / fmaxf((float)(gstart[g + 1] - gstart[g]), 1.0f);
        float o = 0.f;
#pragma unroll 8
        for (int hh = 0; hh < 64; ++hh) o += pgs[s * 64 + hh] * clas_w[hh * 4 + cc];
        if (o != 0.f) atomicAdd(&gout[g * 4 + cc], o * invc);
    }
}

extern "C" void kernel_launch(void* const* d_in, const int* in_sizes, int n_in,
                              void* d_out, int out_size, void* d_ws, size_t ws_size,
                              hipStream_t stream) {
    const float* x        = (const float*)d_in[0];
    const int* edge_index = (const int*)d_in[1];
    const int* edge_type  = (const int*)d_in[2];
    const int* batch      = (const int*)d_in[3];
    const float* basis1 = (const float*)d_in[4];
    const float* comp1  = (const float*)d_in[5];
    const float* root1  = (const float*)d_in[6];
    const float* bias1  = (const float*)d_in[7];
    const float* basis2 = (const float*)d_in[8];
    const float* comp2  = (const float*)d_in[9];
    const float* root2  = (const float*)d_in[10];
    const float* bias2  = (const float*)d_in[11];
    const float* clas_w = (const float*)d_in[12];
    const float* clas_b = (const float*)d_in[13];

    const int N = in_sizes[0] / 64;
    const int E = in_sizes[2];
    const int G = out_size / 4;
    const int* src = edge_index;
    const int* dst = edge_index + E;
    const int nbuck = (N + 255) >> 8;
    const int build_blocks = (N + 31) / 32;
    const int read_blocks  = (N + 31) / 32;

    char* base = (char*)d_ws;
    size_t off = 0;
    auto carve = [&](size_t bytes) { void* p = base + off; off = (off + bytes + 15) & ~(size_t)15; return p; };
    int*   cur     = (int*)carve(sizeof(int) * 256);
    int*   gstart  = (int*)carve(sizeof(int) * ((size_t)G + 1));
    int*   tmp     = (int*)carve(sizeof(int) * (size_t)nbuck * CAP);
    int4*  rp4g    = (int4*)carve(sizeof(int4) * (size_t)N);
    int*   kendg   = (int*)carve(sizeof(int) * (size_t)N);
    int*   eidxg   = (int*)carve(sizeof(int) * (size_t)build_blocks * VCAP);
    short* W1t     = (short*)carve(sizeof(short) * LWN);
    short* W2t     = (short*)carve(sizeof(short) * LWN);
    short* Xb1     = (short*)carve(sizeof(short) * (size_t)N * 64);
    short* H1      = (short*)carve(sizeof(short) * (size_t)N * 64);
    float* gout    = (float*)d_out;

    const int ebl = (E + EPB - 1) / EPB;
    const int wbl = (2 * LWN + 255) / 256;
    const int nb  = (N + 255) / 256;
    const int gzb = (G * 4 + 255) / 256;
    const int cvb = (N * 64 / 4 + 255) / 256;
    const int work_blocks = ebl + wbl + nb + gzb + cvb;

    hipMemsetAsync(cur, 0, sizeof(int) * 256, stream);

    work_kernel<<<work_blocks, 256, 0, stream>>>(
        src, dst, edge_type, E, cur, tmp,
        basis1, comp1, root1, basis2, comp2, root2, W1t, W2t,
        batch, gstart, N, G, x, Xb1, gout, clas_b, ebl, wbl, nb, gzb);

    layer_build_kernel<<<build_blocks, 256, 0, stream>>>(
        cur, tmp, Xb1, W1t, bias1, H1, N, rp4g, kendg, eidxg);
    layer_read_kernel<<<read_blocks, 256, 0, stream>>>(
        rp4g, kendg, eidxg, H1, W2t, bias2, N, batch, gstart, clas_w, gout);
}

// Round 16
// 203.889 us; speedup vs baseline: 1.0288x; 1.0288x over previous
//
#include <hip/hip_runtime.h>

// H2G2: 2-layer RGCN (R=4, per-relation mean) + mean-pool + linear.
// R10 (231us, layer 47): register-resident fused layer. R11 FAILED: VGPR cap
//   -> scratch spill. R12 (229.6): channel-split wave pair; layer pinned 47.0.
// R13 FAILED: random 4B global writes = line RMW. R14 FAILED: grid.sync
//   ~80-90us each w/ idle grid. R15: CAP-bucket OK; per-element device
//   atomics FAILED (3.2M = 150us). R16 (219.6): 6-dispatch pipeline.
// R17 FAILED: 8-edge unroll -> occ crash. MLP model: layer ~ 1/(waves x
//   depth) until ~96 lines/CU, then per-XCD random-fill-rate floor ~0.9
//   lines/cy (R21 null proves rate-bound). Gather FROZEN. FETCH 52MB compuls.
// R18 (275): 1-block uncached cls = 70us serial tail. R19 (232.4): in-layer
//   CSR paid twice. R20 (218.3): CSR once in build. R22 (229.9): fine bins
//   broke bin write coalescing. R23 (219.4): XCD swizzle killed build
//   over-fetch but Phase A is barrier/latency-bound. R24 (209.4): shuffle
//   scans + sbkt tag -> -10us. R25 (209.8): deleting cls dispatch NEUTRAL ->
//   boundary cost small/fixed; stop chasing gaps.
// R26: Phase A single-pass. INSIGHT: rel-sorted edge lists are unnecessary
//   since R11's one-hot merge (ACCM reads rel bits per edge; iv needs only
//   counts). Replace count+scan+ordered-scatter with ONE pass into fixed
//   48-slot per-node elist regions (P(deg>48)~2e-11), 2 LDS atomics/edge,
//   2 barriers. Persist degg + precomputed ivg(float4) + raw 1536-slot
//   region; read computes k0 = block*1536 + w*48. DECISION: if build moves
//   <3us, Phase A residual is irreducible -> roofline next round.

#define RR 4
#define HH 64
#define KK 320         // (RR+1)*HH
#define LWN (HH * KK)  // weights per layer = 20480
#define EPB 2048       // edges per bin chunk
#define CAP 6144       // per-256-node-bucket capacity (mean 4096, +32 sigma)
#define NSLOT 8        // LDS pool slots
#define DCAP 48        // per-node edge slots (mean 16, P(>48) ~ 2e-11)
#define ECAP (32 * DCAP)  // per-block elist region = 1536

using frag_ab = __attribute__((ext_vector_type(8))) short;
using frag_cd = __attribute__((ext_vector_type(4))) float;

__device__ inline short f2bf(float f) {
    unsigned u = __builtin_bit_cast(unsigned, f);
    unsigned r = u + 0x7fffu + ((u >> 16) & 1u);  // RNE
    return (short)(r >> 16);
}
__device__ inline float bf2f(short s) {
    unsigned u = ((unsigned)(unsigned short)s) << 16;
    return __builtin_bit_cast(float, u);
}

// ---- shared gather accumulate macro ----
#define ACCM(P, F)                                                            \
    {                                                                         \
        int r_ = (P) & 3;                                                     \
        float s0_ = (r_ == 0) ? 1.f : 0.f;                                    \
        float s1_ = (r_ == 1) ? 1.f : 0.f;                                    \
        float s2_ = (r_ == 2) ? 1.f : 0.f;                                    \
        float s3_ = (r_ == 3) ? 1.f : 0.f;                                    \
        _Pragma("unroll") for (int j = 0; j < 8; ++j) {                       \
            float v_ = bf2f((F)[j]);                                          \
            acc[0][j] += v_ * s0_;                                            \
            acc[1][j] += v_ * s1_;                                            \
            acc[2][j] += v_ * s2_;                                            \
            acc[3][j] += v_ * s3_;                                            \
        }                                                                     \
    }

// ---- work: bin(shuffle-scan) | weights | gstart | gout-bias-init | x conv ----
__global__ __launch_bounds__(256) void work_kernel(
    const int* __restrict__ src, const int* __restrict__ dst,
    const int* __restrict__ et, int E,
    int* __restrict__ cur, int* __restrict__ tmp,
    const float* __restrict__ basis1, const float* __restrict__ comp1, const float* __restrict__ root1,
    const float* __restrict__ basis2, const float* __restrict__ comp2, const float* __restrict__ root2,
    short* __restrict__ W1t, short* __restrict__ W2t,
    const int* __restrict__ batch, int* __restrict__ gstart, int N, int G,
    const float* __restrict__ x, short* __restrict__ Xb,
    float* __restrict__ gout, const float* __restrict__ clas_b,
    int ebl, int wbl, int nb, int gzb) {
    __shared__ int hist[256];
    __shared__ int lscan[256];
    __shared__ int lbase[256];
    __shared__ int lc2[256];
    __shared__ int wsum[4];
    __shared__ int sbuf[EPB];
    __shared__ unsigned char sbkt[EPB];
    const int bid = blockIdx.x;
    const int t = threadIdx.x;

    if (bid < ebl) {  // ---- bin: LDS-staged bucket scatter into CAP regions ----
        const int e0 = bid * EPB;
        const int e1 = min(e0 + EPB, E);
        hist[t] = 0;
        __syncthreads();
        for (int e = e0 + t; e < e1; e += 256) atomicAdd(&hist[dst[e] >> 8], 1);
        __syncthreads();
        int v = hist[t];
        // shuffle inclusive scan over 256 threads (4 waves)
        const int lane = t & 63, w = t >> 6;
        int sv = v;
#pragma unroll
        for (int off = 1; off < 64; off <<= 1) {
            int u = __shfl_up(sv, off, 64);
            if (lane >= off) sv += u;
        }
        if (lane == 63) wsum[w] = sv;
        __syncthreads();
        int wpre = 0;
#pragma unroll
        for (int i = 0; i < 4; ++i) wpre += (i < w) ? wsum[i] : 0;
        sv += wpre;                 // inclusive
        lscan[t] = sv - v;          // exclusive
        lbase[t] = v ? t * CAP + atomicAdd(&cur[t], v) : 0;  // reserve
        lc2[t] = 0;
        __syncthreads();
        for (int e = e0 + t; e < e1; e += 256) {
            int d = dst[e];
            int b = d >> 8;
            int p = (src[e] << 10) | (et[e] << 8) | (d & 255);
            int pos = lscan[b] + atomicAdd(&lc2[b], 1);
            sbuf[pos] = p;
            sbkt[pos] = (unsigned char)b;
        }
        __syncthreads();
        int tot = e1 - e0;
        for (int i = t; i < tot; i += 256) {
            int b = sbkt[i];
            int idx = lbase[b] + (i - lscan[b]);
            if (idx - b * CAP < CAP) tmp[idx] = sbuf[i];  // overflow shield
        }
    } else if (bid < ebl + wbl) {  // ---- weights: Wt[c*320+k] = Wstack[k][c] ----
        int w = (bid - ebl) * 256 + t;
        int layer = w / LWN;
        int rem = w - layer * LWN;
        int c = rem / KK;
        int k = rem - c * KK;
        const float* basis = layer ? basis2 : basis1;
        const float* comp  = layer ? comp2  : comp1;
        const float* root  = layer ? root2  : root1;
        short* Wt          = layer ? W2t    : W1t;
        float v;
        if (k < HH) {
            v = root[k * HH + c];
        } else {
            int r = (k >> 6) - 1, kk = k & 63;
            v = 0.f;
#pragma unroll
            for (int b = 0; b < RR; ++b) v += comp[r * RR + b] * basis[(b * HH + kk) * HH + c];
        }
        Wt[c * KK + k] = f2bf(v);
    } else if (bid < ebl + wbl + nb) {  // ---- gstart ----
        int i = (bid - ebl - wbl) * 256 + t;
        if (i < N) {
            int b1 = batch[i];
            int b0 = (i == 0) ? -1 : batch[i - 1];
            for (int g = b0 + 1; g <= b1; ++g) gstart[g] = i;
            if (i == N - 1)
                for (int g = b1 + 1; g <= G; ++g) gstart[g] = N;
        }
    } else if (bid < ebl + wbl + nb + gzb) {  // ---- gout = bias (classifier base) ----
        int i = (bid - ebl - wbl - nb) * 256 + t;
        if (i < G * 4) gout[i] = clas_b[i & 3];
    } else {  // ---- convert x fp32 -> bf16 ----
        int i4 = (bid - ebl - wbl - nb - gzb) * 256 + t;
        int base = i4 * 4;
        if (base < N * 64) {
            float4 f = *(const float4*)&x[base];
            short4 s;
            s.x = f2bf(f.x); s.y = f2bf(f.y); s.z = f2bf(f.z); s.w = f2bf(f.w);
            *(short4*)&Xb[base] = s;
        }
    }
}

// ---- layer_build (L1, 256 thr / 32 nodes, XCD-swizzled): SINGLE-PASS
//      Phase A (fixed 48-slot/node regions, no scan) -> persist degg/ivg/
//      eidxg; Phase B = FROZEN gather from LDS elist. ----
__global__ __launch_bounds__(256) void layer_build_kernel(
    const int* __restrict__ curg,
    const int* __restrict__ tmp,
    const short* __restrict__ Xb,
    const short* __restrict__ Wt,
    const float* __restrict__ bias,
    short* __restrict__ out, int n,
    int* __restrict__ degg, float4* __restrict__ ivg,
    int* __restrict__ eidxg) {
    __shared__ short xpack[2][64][32];  // 8KB
    __shared__ int cnt4[128];           // per (node,rel) counts (for iv)
    __shared__ int curw[32];            // per-node placement cursors
    __shared__ int elist[ECAP];         // 6KB: node-grouped (unsorted rel)
    const int t = threadIdx.x;
    const int wv = t >> 6;
    const int pair = wv >> 1;
    const int ws = wv & 1;
    const int l = t & 63;
    const int m = l & 15;
    const int quad = l >> 4;

    // ---- XCD-aware bijective swizzle (m204): bucket's 8 blocks -> one XCD ----
    const int nwg = (int)gridDim.x;
    const int orig = blockIdx.x;
    const int q = nwg >> 3, r = nwg & 7;
    const int xcd = orig & 7, idx = orig >> 3;
    const int chunk = (xcd < r ? xcd * (q + 1) : r * (q + 1) + (xcd - r) * q) + idx;

    const int node0 = chunk * 32;
    const int node = node0 + pair * 16 + m;
    const bool valid = node < n;

    // ---- Phase A: single pass ----
    const int b = node0 >> 8;
    const int dl0 = node0 & 255;
    const int tb = b * CAP;
    const int len = min(curg[b], CAP);

    for (int i = t; i < 128; i += 256) cnt4[i] = 0;
    if (t < 32) curw[t] = 0;
    __syncthreads();
    for (int i = t; i < len; i += 256) {
        int e = tmp[tb + i];
        int w = (e & 255) - dl0;
        if ((unsigned)w < 32u) {
            int rel = (e >> 8) & 3;
            int pos = atomicAdd(&curw[w], 1);
            if (pos < DCAP) elist[w * DCAP + pos] = ((e >> 10) << 2) | rel;
            atomicAdd(&cnt4[(w << 2) | rel], 1);
        }
    }
    __syncthreads();

    // ---- persist CSR (overlaps with Phase B issue) ----
    const int eb = chunk * ECAP;
    if (t < 32 && node0 + t < n) {
        degg[node0 + t] = min(curw[t], DCAP);
        float4 ivp;
        ivp.x = 1.0f / fmaxf((float)cnt4[t * 4 + 0], 1.0f);
        ivp.y = 1.0f / fmaxf((float)cnt4[t * 4 + 1], 1.0f);
        ivp.z = 1.0f / fmaxf((float)cnt4[t * 4 + 2], 1.0f);
        ivp.w = 1.0f / fmaxf((float)cnt4[t * 4 + 3], 1.0f);
        ivg[node0 + t] = ivp;
    }
    for (int i4 = t * 4; i4 < ECAP; i4 += 1024)
        *(int4*)&eidxg[eb + i4] = *(const int4*)&elist[i4];

    // ---- Phase B: FROZEN gather from LDS elist ----
    float acc[4][8];
#pragma unroll
    for (int r2 = 0; r2 < 4; ++r2)
#pragma unroll
        for (int j = 0; j < 8; ++j) acc[r2][j] = 0.f;

    const int w = (pair << 4) | m;
    const int k0 = w * DCAP;
    const int k1 = k0 + min(curw[w], DCAP);
    float4 iv;
    iv.x = 1.0f / fmaxf((float)cnt4[w * 4 + 0], 1.0f);
    iv.y = 1.0f / fmaxf((float)cnt4[w * 4 + 1], 1.0f);
    iv.z = 1.0f / fmaxf((float)cnt4[w * 4 + 2], 1.0f);
    iv.w = 1.0f / fmaxf((float)cnt4[w * 4 + 3], 1.0f);
    const short* xbq = Xb + ws * 32 + quad * 8;

    int k = k0;
    for (; k + 3 < k1; k += 4) {
        int p0 = elist[k];
        int p1 = elist[k + 1];
        int p2 = elist[k + 2];
        int p3 = elist[k + 3];
        const short* a0p = xbq + (size_t)(p0 >> 2) * 64;
        const short* a1p = xbq + (size_t)(p1 >> 2) * 64;
        const short* a2p = xbq + (size_t)(p2 >> 2) * 64;
        const short* a3p = xbq + (size_t)(p3 >> 2) * 64;
        frag_ab f0 = *(const frag_ab*)a0p;
        frag_ab f1 = *(const frag_ab*)a1p;
        frag_ab f2 = *(const frag_ab*)a2p;
        frag_ab f3 = *(const frag_ab*)a3p;
        ACCM(p0, f0)
        ACCM(p1, f1)
        ACCM(p2, f2)
        ACCM(p3, f3)
    }
    for (; k < k1; ++k) {
        int p0 = elist[k];
        const short* a0p = xbq + (size_t)(p0 >> 2) * 64;
        frag_ab f0 = *(const frag_ab*)a0p;
        ACCM(p0, f0)
    }

    frag_ab y[4];
    {
        float s0 = iv.x, s1 = iv.y, s2 = iv.z, s3 = iv.w;
#pragma unroll
        for (int j = 0; j < 8; ++j) {
            y[0][j] = f2bf(acc[0][j] * s0);
            y[1][j] = f2bf(acc[1][j] * s1);
            y[2][j] = f2bf(acc[2][j] * s2);
            y[3][j] = f2bf(acc[3][j] * s3);
        }
    }

    if (ws == 1) {
#pragma unroll
        for (int r2 = 0; r2 < 4; ++r2)
            *(frag_ab*)&xpack[pair][l][r2 * 8] = y[r2];
    }
    __syncthreads();
    if (ws == 1) return;

    frag_ab a[10];
    a[0] = frag_ab{};
    a[1] = frag_ab{};
    if (valid) {
        const short* xr = Xb + (size_t)node * 64 + quad * 8;
        a[0] = *(const frag_ab*)xr;
        a[1] = *(const frag_ab*)(xr + 32);
    }
#pragma unroll
    for (int r2 = 0; r2 < 4; ++r2) {
        a[2 + 2 * r2] = y[r2];
        a[3 + 2 * r2] = *(const frag_ab*)&xpack[pair][l][r2 * 8];
    }

    const int nrow_base = node0 + pair * 16 + quad * 4;
#pragma unroll
    for (int ct = 0; ct < 4; ++ct) {
        const short* bp = Wt + (size_t)(ct * 16 + m) * KK + quad * 8;
        frag_cd c = {0.f, 0.f, 0.f, 0.f};
#pragma unroll
        for (int f = 0; f < 10; ++f) {
            frag_ab bf = *(const frag_ab*)(bp + f * 32);
            c = __builtin_amdgcn_mfma_f32_16x16x32_bf16(a[f], bf, c, 0, 0, 0);
        }
        int col = ct * 16 + m;
        float bv = bias[col];
#pragma unroll
        for (int r2 = 0; r2 < 4; ++r2) {
            int nr = nrow_base + r2;
            if (nr < n) out[(size_t)nr * 64 + col] = f2bf(fmaxf(c[r2] + bv, 0.f));
        }
    }
}

// ---- layer_read (L2, 256 thr / 32 nodes): gather from persisted fixed-slot
//      CSR + LDS-first pooling + commuted classifier -> gout atomics. ----
__global__ __launch_bounds__(256) void layer_read_kernel(
    const int* __restrict__ degg, const float4* __restrict__ ivg,
    const int* __restrict__ eidxg,
    const short* __restrict__ Xb,
    const short* __restrict__ Wt,
    const float* __restrict__ bias,
    int n, const int* __restrict__ batch,
    const int* __restrict__ gstart, const float* __restrict__ clas_w,
    float* __restrict__ gout) {
    __shared__ short xpack[2][64][32];  // 8KB
    __shared__ float pgs[NSLOT * 64];   // 2KB
    const int t = threadIdx.x;
    const int wv = t >> 6;
    const int pair = wv >> 1;
    const int ws = wv & 1;
    const int l = t & 63;
    const int m = l & 15;
    const int quad = l >> 4;
    const int node0 = blockIdx.x * 32;
    const int node = node0 + pair * 16 + m;
    const bool valid = node < n;

    for (int i = t; i < NSLOT * 64; i += 256) pgs[i] = 0.f;

    float acc[4][8];
#pragma unroll
    for (int r = 0; r < 4; ++r)
#pragma unroll
        for (int j = 0; j < 8; ++j) acc[r][j] = 0.f;

    int k0 = 0, k1 = 0;
    float4 iv = make_float4(0.f, 0.f, 0.f, 0.f);
    if (valid) {
        int w = pair * 16 + m;
        k0 = blockIdx.x * ECAP + w * DCAP;
        k1 = k0 + degg[node];
        iv = ivg[node];
    }
    const short* xbq = Xb + ws * 32 + quad * 8;

    int k = k0;
    for (; k + 3 < k1; k += 4) {  // FROZEN 4-deep
        int p0 = eidxg[k];
        int p1 = eidxg[k + 1];
        int p2 = eidxg[k + 2];
        int p3 = eidxg[k + 3];
        const short* a0p = xbq + (size_t)(p0 >> 2) * 64;
        const short* a1p = xbq + (size_t)(p1 >> 2) * 64;
        const short* a2p = xbq + (size_t)(p2 >> 2) * 64;
        const short* a3p = xbq + (size_t)(p3 >> 2) * 64;
        frag_ab f0 = *(const frag_ab*)a0p;
        frag_ab f1 = *(const frag_ab*)a1p;
        frag_ab f2 = *(const frag_ab*)a2p;
        frag_ab f3 = *(const frag_ab*)a3p;
        ACCM(p0, f0)
        ACCM(p1, f1)
        ACCM(p2, f2)
        ACCM(p3, f3)
    }
    for (; k < k1; ++k) {
        int p0 = eidxg[k];
        const short* a0p = xbq + (size_t)(p0 >> 2) * 64;
        frag_ab f0 = *(const frag_ab*)a0p;
        ACCM(p0, f0)
    }

    frag_ab y[4];
    {
        float s0 = iv.x, s1 = iv.y, s2 = iv.z, s3 = iv.w;
#pragma unroll
        for (int j = 0; j < 8; ++j) {
            y[0][j] = f2bf(acc[0][j] * s0);
            y[1][j] = f2bf(acc[1][j] * s1);
            y[2][j] = f2bf(acc[2][j] * s2);
            y[3][j] = f2bf(acc[3][j] * s3);
        }
    }

    if (ws == 1) {
#pragma unroll
        for (int r = 0; r < 4; ++r)
            *(frag_ab*)&xpack[pair][l][r * 8] = y[r];
    }
    __syncthreads();

    const int nrow_base = node0 + pair * 16 + quad * 4;
    const int batch_base = batch[node0];

    if (ws == 0) {
        frag_ab a[10];
        a[0] = frag_ab{};
        a[1] = frag_ab{};
        if (valid) {
            const short* xr = Xb + (size_t)node * 64 + quad * 8;
            a[0] = *(const frag_ab*)xr;
            a[1] = *(const frag_ab*)(xr + 32);
        }
#pragma unroll
        for (int r = 0; r < 4; ++r) {
            a[2 + 2 * r] = y[r];
            a[3 + 2 * r] = *(const frag_ab*)&xpack[pair][l][r * 8];
        }

        int bv4[4];
        if (nrow_base + 3 < n) {
            int4 bb = *(const int4*)&batch[nrow_base];
            bv4[0] = bb.x; bv4[1] = bb.y; bv4[2] = bb.z; bv4[3] = bb.w;
        } else {
#pragma unroll
            for (int r = 0; r < 4; ++r)
                bv4[r] = (nrow_base + r < n) ? batch[nrow_base + r] : 0;
        }

#pragma unroll
        for (int ct = 0; ct < 4; ++ct) {
            const short* bp = Wt + (size_t)(ct * 16 + m) * KK + quad * 8;
            frag_cd c = {0.f, 0.f, 0.f, 0.f};
#pragma unroll
            for (int f = 0; f < 10; ++f) {
                frag_ab bf = *(const frag_ab*)(bp + f * 32);
                c = __builtin_amdgcn_mfma_f32_16x16x32_bf16(a[f], bf, c, 0, 0, 0);
            }
            int col = ct * 16 + m;
            float bv = bias[col];
#pragma unroll
            for (int r = 0; r < 4; ++r) {
                int nr = nrow_base + r;
                if (nr < n) {
                    float v = fmaxf(c[r] + bv, 0.f);
                    int g = bv4[r] - batch_base;
                    if (g < NSLOT) {
                        atomicAdd(&pgs[g * 64 + col], v);
                    } else {
                        // rare overflow: commuted classifier per element
                        int gg = bv4[r];
                        float invc = 1.0f / fmaxf((float)(gstart[gg + 1] - gstart[gg]), 1.0f);
                        float vm = v * invc;
#pragma unroll
                        for (int cc = 0; cc < 4; ++cc)
                            atomicAdd(&gout[gg * 4 + cc], vm * clas_w[col * 4 + cc]);
                    }
                }
            }
        }
    }

    __syncthreads();
    // ---- commuted classifier: pgs[s][:] @ clas_w -> 4 atomics per slot ----
    int node_last = min(node0 + 31, n - 1);
    int gspan = batch[node_last] - batch_base;
    int nslots = min(gspan + 1, NSLOT);
    if (t < nslots * 4) {
        int s = t >> 2, cc = t & 3;
        int g = batch_base + s;
        float invc = 1.0f / fmaxf((float)(gstart[g + 1] - gstart[g]), 1.0f);
        float o = 0.f;
#pragma unroll 8
        for (int hh = 0; hh < 64; ++hh) o += pgs[s * 64 + hh] * clas_w[hh * 4 + cc];
        if (o != 0.f) atomicAdd(&gout[g * 4 + cc], o * invc);
    }
}

extern "C" void kernel_launch(void* const* d_in, const int* in_sizes, int n_in,
                              void* d_out, int out_size, void* d_ws, size_t ws_size,
                              hipStream_t stream) {
    const float* x        = (const float*)d_in[0];
    const int* edge_index = (const int*)d_in[1];
    const int* edge_type  = (const int*)d_in[2];
    const int* batch      = (const int*)d_in[3];
    const float* basis1 = (const float*)d_in[4];
    const float* comp1  = (const float*)d_in[5];
    const float* root1  = (const float*)d_in[6];
    const float* bias1  = (const float*)d_in[7];
    const float* basis2 = (const float*)d_in[8];
    const float* comp2  = (const float*)d_in[9];
    const float* root2  = (const float*)d_in[10];
    const float* bias2  = (const float*)d_in[11];
    const float* clas_w = (const float*)d_in[12];
    const float* clas_b = (const float*)d_in[13];

    const int N = in_sizes[0] / 64;
    const int E = in_sizes[2];
    const int G = out_size / 4;
    const int* src = edge_index;
    const int* dst = edge_index + E;
    const int nbuck = (N + 255) >> 8;
    const int build_blocks = (N + 31) / 32;
    const int read_blocks  = (N + 31) / 32;

    char* base = (char*)d_ws;
    size_t off = 0;
    auto carve = [&](size_t bytes) { void* p = base + off; off = (off + bytes + 15) & ~(size_t)15; return p; };
    int*    cur     = (int*)carve(sizeof(int) * 256);
    int*    gstart  = (int*)carve(sizeof(int) * ((size_t)G + 1));
    int*    tmp     = (int*)carve(sizeof(int) * (size_t)nbuck * CAP);
    int*    degg    = (int*)carve(sizeof(int) * (size_t)N);
    float4* ivg     = (float4*)carve(sizeof(float4) * (size_t)N);
    int*    eidxg   = (int*)carve(sizeof(int) * (size_t)build_blocks * ECAP);
    short*  W1t     = (short*)carve(sizeof(short) * LWN);
    short*  W2t     = (short*)carve(sizeof(short) * LWN);
    short*  Xb1     = (short*)carve(sizeof(short) * (size_t)N * 64);
    short*  H1      = (short*)carve(sizeof(short) * (size_t)N * 64);
    float*  gout    = (float*)d_out;

    const int ebl = (E + EPB - 1) / EPB;
    const int wbl = (2 * LWN + 255) / 256;
    const int nb  = (N + 255) / 256;
    const int gzb = (G * 4 + 255) / 256;
    const int cvb = (N * 64 / 4 + 255) / 256;
    const int work_blocks = ebl + wbl + nb + gzb + cvb;

    hipMemsetAsync(cur, 0, sizeof(int) * 256, stream);

    work_kernel<<<work_blocks, 256, 0, stream>>>(
        src, dst, edge_type, E, cur, tmp,
        basis1, comp1, root1, basis2, comp2, root2, W1t, W2t,
        batch, gstart, N, G, x, Xb1, gout, clas_b, ebl, wbl, nb, gzb);

    layer_build_kernel<<<build_blocks, 256, 0, stream>>>(
        cur, tmp, Xb1, W1t, bias1, H1, N, degg, ivg, eidxg);
    layer_read_kernel<<<read_blocks, 256, 0, stream>>>(
        degg, ivg, eidxg, H1, W2t, bias2, N, batch, gstart, clas_w, gout);
}